// Round 2
// baseline (154.772 us; speedup 1.0000x reference)
//
#include <hip/hip_runtime.h>
#include <cfloat>
#include <climits>

#define NN 50000
#define NE 800000
#define IND 128
#define NH 4
#define L1D 256   // NH * 64
#define OUTD 64
#define SLOPE 0.2f

#define MAXE2 1024
#define MAXU1 1024
#define MAXE1 32768
#define MAXU0 8192
#define CAP 512

// ---------- K0: init ws header + flags, detect int64 vs int32 edge_index ----------
__global__ void k0_init(int* hdr, int* flag1, int* idx0, const int* ei32) {
  int gid = blockIdx.x * blockDim.x + threadIdx.x;
  for (int i = gid; i < NN; i += gridDim.x * blockDim.x) { flag1[i] = -1; idx0[i] = -1; }
  if (gid == 0) {
    hdr[0] = INT_MAX;               // root candidate (atomicMin)
    hdr[1] = 0;                     // cnt edges into root
    hdr[2] = 0;                     // cnt unique 1-hop frontier U1
    hdr[3] = 0;                     // cnt edges into frontier
    hdr[4] = 0;                     // cnt unique 2-hop set U0
    hdr[5] = 0;
    hdr[6] = 0;
    // int64 detection: node ids < 2^31 -> every odd int32 slot is 0 (LE)
    int is64 = 1;
    for (int k = 0; k < 16; ++k) if (ei32[2 * k + 1] != 0) { is64 = 0; break; }
    hdr[7] = is64;
  }
}

// ---------- K1: find root = min i with x[i,0] == 0 ----------
__global__ void k1_root(const float* x, int* hdr) {
  int i = blockIdx.x * blockDim.x + threadIdx.x;
  if (i < NN && x[(size_t)i * IND] == 0.0f) atomicMin(&hdr[0], i);
}

__device__ __forceinline__ int get_src(const int* p, int is64, int e) {
  return is64 ? p[2 * e] : p[e];
}
__device__ __forceinline__ int get_dst(const int* p, int is64, int e) {
  return is64 ? p[2 * NE + 2 * e] : p[NE + e];
}

// ---------- K2: collect edges with dst == root; mark 1-hop frontier U1 ----------
__global__ void k2_scan_root(const int* ei, int* hdr, int* e2_src, int* u1_list, int* flag1) {
  int e = blockIdx.x * blockDim.x + threadIdx.x;
  int is64 = hdr[7];
  int root = hdr[0]; if (root < 0 || root >= NN) root = 0;
  auto mark_u1 = [&](int j) {
    if (atomicCAS(&flag1[j], -1, -2) == -1) {
      int p = atomicAdd(&hdr[2], 1);
      if (p < MAXU1) { u1_list[p] = j; flag1[j] = p; }
    }
  };
  if (e < NE) {
    int dst = get_dst(ei, is64, e);
    if (dst == root) {
      int pos = atomicAdd(&hdr[1], 1);
      int src = get_src(ei, is64, e);
      if (pos < MAXE2) e2_src[pos] = src;
      mark_u1(src);
    }
  }
  if (e == 0) {  // reference appends a self-loop for every node
    int pos = atomicAdd(&hdr[1], 1);
    if (pos < MAXE2) e2_src[pos] = root;
    mark_u1(root);
  }
}

// ---------- K3: collect edges with dst in U1; mark 2-hop set U0 ----------
__global__ void k3_scan_l1(const int* ei, int* hdr, const int* flag1,
                           int* e1_src, int* e1_dst, int* idx0, int* u0_list) {
  int e = blockIdx.x * blockDim.x + threadIdx.x;
  if (e >= NE) return;
  int is64 = hdr[7];
  int dst = get_dst(ei, is64, e);
  if (dst >= 0 && dst < NN && flag1[dst] >= 0) {
    int pos = atomicAdd(&hdr[3], 1);
    if (pos < MAXE1) {
      int src = get_src(ei, is64, e);
      e1_src[pos] = src; e1_dst[pos] = dst;
      if (atomicCAS(&idx0[src], -1, -2) == -1) {
        int p = atomicAdd(&hdr[4], 1);
        if (p < MAXU0) { u0_list[p] = src; idx0[src] = p; }
      }
    }
  }
}

// ---------- K3b: self-loop edges for each frontier node ----------
__global__ void k3b_selfloops(int* hdr, const int* u1_list,
                              int* e1_src, int* e1_dst, int* idx0, int* u0_list) {
  int t = blockIdx.x * blockDim.x + threadIdx.x;
  int n1 = min(hdr[2], MAXU1);
  if (t >= n1) return;
  int u = u1_list[t];
  int pos = atomicAdd(&hdr[3], 1);
  if (pos < MAXE1) { e1_src[pos] = u; e1_dst[pos] = u; }
  if (atomicCAS(&idx0[u], -1, -2) == -1) {
    int p = atomicAdd(&hdr[4], 1);
    if (p < MAXU0) { u0_list[p] = u; idx0[u] = p; }
  }
}

// ---------- K4: h = x[u] @ W1^T for U0; per-head attention logits ----------
__global__ __launch_bounds__(256) void k4_proj1(const float* x, const float* W1,
    const float* att_s, const float* att_d, const int* hdr, const int* u0_list,
    float* h_buf, float* as1, float* ad1) {
  __shared__ float xs[IND];
  int n0 = min(hdr[4], MAXU0);
  int t = threadIdx.x;
  for (int i = blockIdx.x; i < n0; i += gridDim.x) {
    int u = u0_list[i];
    __syncthreads();
    if (t < IND) xs[t] = x[(size_t)u * IND + t];
    __syncthreads();
    float acc = 0.f;
    const float* wrow = W1 + (size_t)t * IND;
    #pragma unroll 4
    for (int c = 0; c < IND; ++c) acc += xs[c] * wrow[c];
    h_buf[(size_t)i * L1D + t] = acc;
    float ps = acc * att_s[t];
    float pd = acc * att_d[t];
    #pragma unroll
    for (int off = 32; off > 0; off >>= 1) {
      ps += __shfl_down(ps, off, 64);
      pd += __shfl_down(pd, off, 64);
    }
    int lane = t & 63, head = t >> 6;   // block = 4 waves, one head each
    if (lane == 0) { as1[i * NH + head] = ps; ad1[i * NH + head] = pd; }
  }
}

// ---------- K5: GAT layer-1 softmax + aggregate for each u in U1 ----------
__global__ __launch_bounds__(256) void k5_gat1(const int* hdr, const int* u1_list,
    const int* e1_src, const int* e1_dst, const int* idx0,
    const float* h_buf, const float* as1, const float* ad1,
    const float* b1, float* h1_buf) {
  __shared__ int lcnt;
  __shared__ int sidx[CAP];
  __shared__ float ev[CAP][NH];
  __shared__ float mh[NH], dh[NH];
  int n1 = min(hdr[2], MAXU1);
  int ne = min(hdr[3], MAXE1);
  int t = threadIdx.x;
  for (int ui = blockIdx.x; ui < n1; ui += gridDim.x) {
    int u = u1_list[ui];
    __syncthreads();
    if (t == 0) lcnt = 0;
    __syncthreads();
    int uidx = idx0[u];
    for (int e = t; e < ne; e += blockDim.x) {
      if (e1_dst[e] == u) {
        int slot = atomicAdd(&lcnt, 1);
        if (slot < CAP) {
          int si = idx0[e1_src[e]];
          sidx[slot] = si;
          #pragma unroll
          for (int hd = 0; hd < NH; ++hd) {
            float v = as1[si * NH + hd] + ad1[uidx * NH + hd];
            ev[slot][hd] = v > 0.f ? v : SLOPE * v;
          }
        }
      }
    }
    __syncthreads();
    int cnt = min(lcnt, CAP);
    if (t < NH) {
      float m = -FLT_MAX;
      for (int k = 0; k < cnt; ++k) m = fmaxf(m, ev[k][t]);
      mh[t] = m;
    }
    __syncthreads();
    for (int idx = t; idx < cnt * NH; idx += blockDim.x) {
      int k = idx >> 2, hd = idx & 3;
      ev[k][hd] = expf(ev[k][hd] - mh[hd]);
    }
    __syncthreads();
    if (t < NH) {
      float s = 0.f;
      for (int k = 0; k < cnt; ++k) s += ev[k][t];
      dh[t] = s + 1e-16f;
    }
    __syncthreads();
    int hd = t >> 6;
    float acc = 0.f;
    for (int k = 0; k < cnt; ++k) acc += ev[k][hd] * h_buf[(size_t)sidx[k] * L1D + t];
    acc = acc / dh[hd] + b1[t];
    h1_buf[(size_t)ui * L1D + t] = acc > 0.f ? acc : 0.f;
  }
}

// ---------- K6: g = h1[u] @ W2^T, layer-2 logits ----------
__global__ __launch_bounds__(64) void k6_proj2(const int* hdr, const int* u1_list,
    const float* h1_buf, const float* W2, const float* att2_s, const float* att2_d,
    float* g_buf, float* as2, float* ad2p) {
  __shared__ float hs[L1D];
  int n1 = min(hdr[2], MAXU1);
  int root = hdr[0]; if (root < 0 || root >= NN) root = 0;
  int t = threadIdx.x;
  for (int ui = blockIdx.x; ui < n1; ui += gridDim.x) {
    __syncthreads();
    for (int c = t; c < L1D; c += 64) hs[c] = h1_buf[(size_t)ui * L1D + c];
    __syncthreads();
    float acc = 0.f;
    const float* wrow = W2 + (size_t)t * L1D;
    #pragma unroll 4
    for (int c = 0; c < L1D; ++c) acc += hs[c] * wrow[c];
    g_buf[ui * OUTD + t] = acc;
    float ps = acc * att2_s[t];
    float pd = acc * att2_d[t];
    #pragma unroll
    for (int off = 32; off > 0; off >>= 1) {
      ps += __shfl_down(ps, off, 64);
      pd += __shfl_down(pd, off, 64);
    }
    if (t == 0) {
      as2[ui] = ps;
      if (u1_list[ui] == root) *ad2p = pd;
    }
  }
}

// ---------- K7: layer-2 softmax+aggregate at root, ReLU, FC, write 64 outputs ----------
__global__ __launch_bounds__(256) void k7_final(const int* hdr, const int* e2_src,
    const int* flag1, const float* g_buf, const float* as2, const float* ad2p,
    const float* b2, const float* Wfc, const float* bfc, float* out) {
  __shared__ float ev[MAXE2];
  __shared__ int jix[MAXE2];
  __shared__ float m_s, d_s;
  __shared__ float h2[OUTD];
  int t = threadIdx.x;
  int ne2 = min(hdr[1], MAXE2);
  float ad2 = *ad2p;
  for (int e = t; e < ne2; e += blockDim.x) {
    int j = e2_src[e];
    int ji = flag1[j];
    jix[e] = ji;
    float v = (ji >= 0 ? as2[ji] : 0.f) + ad2;
    ev[e] = v > 0.f ? v : SLOPE * v;
  }
  __syncthreads();
  if (t == 0) {
    float m = -FLT_MAX;
    for (int e = 0; e < ne2; ++e) m = fmaxf(m, ev[e]);
    m_s = m;
  }
  __syncthreads();
  for (int e = t; e < ne2; e += blockDim.x) ev[e] = expf(ev[e] - m_s);
  __syncthreads();
  if (t == 0) {
    float s = 0.f;
    for (int e = 0; e < ne2; ++e) s += ev[e];
    d_s = s + 1e-16f;
  }
  __syncthreads();
  if (t < OUTD) {
    float acc = 0.f;
    for (int e = 0; e < ne2; ++e) {
      int ji = jix[e];
      if (ji >= 0) acc += ev[e] * g_buf[ji * OUTD + t];
    }
    acc = acc / d_s + b2[t];
    h2[t] = acc > 0.f ? acc : 0.f;
  }
  __syncthreads();
  if (t < OUTD) {
    float y = bfc[t];
    const float* wrow = Wfc + t * OUTD;
    #pragma unroll 4
    for (int c = 0; c < OUTD; ++c) y += h2[c] * wrow[c];
    out[t] = y;
  }
}

extern "C" void kernel_launch(void* const* d_in, const int* in_sizes, int n_in,
                              void* d_out, int out_size, void* d_ws, size_t ws_size,
                              hipStream_t stream) {
  const float* x   = (const float*)d_in[0];
  const int*   ei  = (const int*)d_in[1];
  const float* W1  = (const float*)d_in[2];
  const float* a1s = (const float*)d_in[3];
  const float* a1d = (const float*)d_in[4];
  const float* b1  = (const float*)d_in[5];
  const float* W2  = (const float*)d_in[6];
  const float* a2s = (const float*)d_in[7];
  const float* a2d = (const float*)d_in[8];
  const float* b2  = (const float*)d_in[9];
  const float* Wfc = (const float*)d_in[10];
  const float* bfc = (const float*)d_in[11];
  float* out = (float*)d_out;

  char* w = (char*)d_ws;
  int* hdr     = (int*)w;                     // 8 ints
  int* flag1   = (int*)(w + 256);             // [NN]  node -> U1 index or -1
  int* idx0    = flag1 + NN;                  // [NN]  node -> U0 index or -1
  int* e2_src  = idx0 + NN;                   // [MAXE2]
  int* u1_list = e2_src + MAXE2;              // [MAXU1]
  int* e1_src  = u1_list + MAXU1;             // [MAXE1]
  int* e1_dst  = e1_src + MAXE1;              // [MAXE1]
  int* u0_list = e1_dst + MAXE1;              // [MAXU0]
  float* h_buf  = (float*)(u0_list + MAXU0);  // [MAXU0][256]
  float* as1    = h_buf + (size_t)MAXU0 * L1D;// [MAXU0][4]
  float* ad1    = as1 + (size_t)MAXU0 * NH;   // [MAXU0][4]
  float* h1_buf = ad1 + (size_t)MAXU0 * NH;   // [MAXU1][256]
  float* g_buf  = h1_buf + (size_t)MAXU1 * L1D; // [MAXU1][64]
  float* as2    = g_buf + (size_t)MAXU1 * OUTD; // [MAXU1]
  float* ad2p   = as2 + MAXU1;                // [1]

  hipLaunchKernelGGL(k0_init, dim3(128), dim3(256), 0, stream, hdr, flag1, idx0, ei);
  hipLaunchKernelGGL(k1_root, dim3((NN + 255) / 256), dim3(256), 0, stream, x, hdr);
  hipLaunchKernelGGL(k2_scan_root, dim3((NE + 255) / 256), dim3(256), 0, stream, ei, hdr, e2_src, u1_list, flag1);
  hipLaunchKernelGGL(k3_scan_l1, dim3((NE + 255) / 256), dim3(256), 0, stream, ei, hdr, flag1, e1_src, e1_dst, idx0, u0_list);
  hipLaunchKernelGGL(k3b_selfloops, dim3((MAXU1 + 255) / 256), dim3(256), 0, stream, hdr, u1_list, e1_src, e1_dst, idx0, u0_list);
  hipLaunchKernelGGL(k4_proj1, dim3(320), dim3(256), 0, stream, x, W1, a1s, a1d, hdr, u0_list, h_buf, as1, ad1);
  hipLaunchKernelGGL(k5_gat1, dim3(32), dim3(256), 0, stream, hdr, u1_list, e1_src, e1_dst, idx0, h_buf, as1, ad1, b1, h1_buf);
  hipLaunchKernelGGL(k6_proj2, dim3(32), dim3(64), 0, stream, hdr, u1_list, h1_buf, W2, a2s, a2d, g_buf, as2, ad2p);
  hipLaunchKernelGGL(k7_final, dim3(1), dim3(256), 0, stream, hdr, e2_src, flag1, g_buf, as2, ad2p, b2, Wfc, bfc, out);
}